// Round 11
// baseline (315.241 us; speedup 1.0000x reference)
//
#include <hip/hip_runtime.h>
#include <hip/hip_bf16.h>
#include <stdint.h>

// ConvNACCell: out[n,co,h,w] = sum_{ci,kh,kw} x[n,ci,h+kh-1,w+kw-1] * W[co,ci,kh,kw]
// W = tanh(W_hat)*sigmoid(M_hat). Implicit GEMM, mfma_f32_16x16x32_bf16.
// Pass 1: x fp32 NCHW -> bf16 NHWC (ws). Pass 2: conv7 = conv6 skeleton
// (A in registers, 256-thread blocks, global_load_lds x-ring) with the
// sync structure upgraded: 8-slot ring, lookahead-2, counted
// s_waitcnt vmcnt(6) + raw s_barrier (never drain vmcnt to 0 in the loop).
// R10 evidence: conv6 ~240us vs 109us HBM floor with clean spill tripwires
// -> duty-cycle limited by the __syncthreads vmcnt(0) drain each chunk.

#define CH_IN  64
#define CH_OUT 128
#define HW     256

typedef __attribute__((ext_vector_type(8))) short short8;   // 8 bf16
typedef __attribute__((ext_vector_type(4))) float f32x4;

// ws layout (bytes)
#define ZP_BYTE  147456u
#define XB_BYTE  147712u
#define WS_NEED  (147712ull + 134217728ull)

#define SLOT_B  8448          // one input row: 528 granules (66 px * 8 g) * 16 B
#define NSLOT   8             // ring slots (power of 2: slot = L & 7)

static __device__ __forceinline__ uint32_t pack_bf16(float a, float b) {
    uint32_t ua = __builtin_bit_cast(uint32_t, a);
    uint32_t ub = __builtin_bit_cast(uint32_t, b);
    ua = (ua + 0x7FFFu + ((ua >> 16) & 1u)) >> 16;
    ub = (ub + 0x7FFFu + ((ub >> 16) & 1u));
    return (ua & 0xFFFFu) | (ub & 0xFFFF0000u);
}

// ---------------------------------------------------------------------------
// Prep: 16x16x32 A-fragment table + zero page.
//   frag[t][ms(8)][s(2)][lane]: elem j = A[co = ms*16 + (lane&15)]
//                                        [ci = s*32 + (lane>>4)*8 + j], tap t.
// ---------------------------------------------------------------------------
__global__ void __launch_bounds__(256) nac_prep16(const float* __restrict__ Wh,
                                                  const float* __restrict__ Mh,
                                                  uint32_t* __restrict__ ws32) {
    if (blockIdx.x == 0 && threadIdx.x < 64) ws32[ZP_BYTE / 4 + threadIdx.x] = 0;

    int f = blockIdx.x * 256 + threadIdx.x;   // 0..9215
    if (f >= 9 * 8 * 2 * 64) return;
    int lane = f & 63;
    int s    = (f >> 6) & 1;
    int ms   = (f >> 7) & 7;
    int t    = f >> 10;
    int co   = ms * 16 + (lane & 15);
    int ci0  = s * 32 + ((lane >> 4) << 3);

    uint32_t pk[4];
#pragma unroll
    for (int j2 = 0; j2 < 4; ++j2) {
        int ci = ci0 + 2 * j2;
        int k0 = ci * 9 + t;
        int k1 = k0 + 9;
        float w0 = tanhf(Wh[co * 576 + k0]);
        float m0 = Mh[co * 576 + k0];
        float w1 = tanhf(Wh[co * 576 + k1]);
        float m1 = Mh[co * 576 + k1];
        float v0 = w0 * (1.0f / (1.0f + expf(-m0)));
        float v1 = w1 * (1.0f / (1.0f + expf(-m1)));
        pk[j2] = pack_bf16(v0, v1);
    }
    int fragidx = ((t * 8 + ms) * 2 + s) * 64 + lane;
    reinterpret_cast<uint4*>(ws32)[fragidx] = make_uint4(pk[0], pk[1], pk[2], pk[3]);
}

// ---------------------------------------------------------------------------
// Convert: x [16,64,256,256] fp32 NCHW -> xb [16,256,256,64] bf16 NHWC.
// ---------------------------------------------------------------------------
__global__ void __launch_bounds__(256) nac_convert(const float* __restrict__ x,
                                                   uint32_t* __restrict__ xb) {
    int bid = blockIdx.x;            // 4096
    int h   = bid & 255;
    int n   = bid >> 8;
    int px  = threadIdx.x;
    const float* xr = x + ((size_t)n * CH_IN * HW + h) * HW + px;
    uint32_t* orow = xb + ((size_t)(n * HW + h) * HW + px) * 32;
#pragma unroll
    for (int g = 0; g < 8; ++g) {
        float v0 = xr[(size_t)(g * 8 + 0) * HW * HW];
        float v1 = xr[(size_t)(g * 8 + 1) * HW * HW];
        float v2 = xr[(size_t)(g * 8 + 2) * HW * HW];
        float v3 = xr[(size_t)(g * 8 + 3) * HW * HW];
        float v4 = xr[(size_t)(g * 8 + 4) * HW * HW];
        float v5 = xr[(size_t)(g * 8 + 5) * HW * HW];
        float v6 = xr[(size_t)(g * 8 + 6) * HW * HW];
        float v7 = xr[(size_t)(g * 8 + 7) * HW * HW];
        uint4 wd;
        wd.x = pack_bf16(v0, v1); wd.y = pack_bf16(v2, v3);
        wd.z = pack_bf16(v4, v5); wd.w = pack_bf16(v6, v7);
        *reinterpret_cast<uint4*>(orow + g * 4) = wd;
    }
}

// ---------------------------------------------------------------------------
// Conv7. Block = 64co x 16h x 64w, 256 threads, 4 waves = (wq co-quarter) x
// (wn row). A slice (36 frags) in 144 VGPR. LDS ring: 8 slots, slot L&7 =
// input row hh = h0+L-1 (66 px x 8 g, granule (px,g) stores ci-octet
// g^(px&7)). Chunk c: reads slots (2c..2c+3)&7, issues rows 2c+6,2c+7
// (lookahead-2). Barrier = counted s_waitcnt vmcnt(6) + raw s_barrier:
// this chunk's 6 DMA stay in flight across the barrier; everything older
// (prev DMA batch, prev stores) is drained. Per-wave VMEM counts uniform
// (tail DMA issued by lanes<16 of EVERY wave; idempotent).
// ---------------------------------------------------------------------------
__global__ void __launch_bounds__(256, 2)
nac_conv7(const uint32_t* __restrict__ xb, const uint32_t* __restrict__ Af,
          float* __restrict__ out, const uint32_t* __restrict__ zp) {
    __shared__ __align__(1024) uint32_t xl[NSLOT * SLOT_B / 4];   // 67,584 B

    unsigned bid = blockIdx.x;
    unsigned idx = (bid & 7u) * 256u + (bid >> 3);   // bijective XCD swizzle
    const int cosplit = idx & 1;
    const int ht = (idx >> 1) & 15;
    const int wt = (idx >> 5) & 3;
    const int n  = idx >> 7;
    const int h0 = ht * 16, w0 = wt * 64;

    const int tid  = threadIdx.x;
    const int lane = tid & 63;
    const int wv   = tid >> 6;      // 0..3
    const int wq   = wv >> 1;       // co quarter within the cosplit half
    const int wn   = wv & 1;        // row within chunk
    const int col  = lane & 15;
    const int row4 = lane >> 4;

    const char* xbn = reinterpret_cast<const char*>(xb) + ((size_t)n << 23);
    const char* lb  = reinterpret_cast<const char*>(xl);

    // ---- A slice into registers: 36 frags, coalesced 1KB loads, L2-hot ----
    const short8* Afr = reinterpret_cast<const short8*>(Af);
    short8 areg[9][2][2];
#pragma unroll
    for (int t = 0; t < 9; ++t)
#pragma unroll
        for (int mi = 0; mi < 2; ++mi)
#pragma unroll
            for (int s = 0; s < 2; ++s)
                areg[t][mi][s] =
                    Afr[((t * 8 + cosplit * 4 + wq * 2 + mi) * 2 + s) * 64 + lane];

    // ---- stage one input row into one ring slot: exactly 3 VMEM per wave ----
    auto stage_row = [&](int slot, int hh) {
#pragma unroll
        for (int pass = 0; pass < 2; ++pass) {
            const int jr = pass * 256 + tid;       // 0..511
            const int px = jr >> 3;
            const int g  = jr & 7;
            const int ww = w0 - 1 + px;
            const bool v = ((unsigned)hh < 256u) & ((unsigned)ww < 256u);
            const uint32_t* src = v
                ? (const uint32_t*)(xbn + ((size_t)(hh * 256 + ww) << 7)
                                        + ((g ^ (px & 7)) << 4))
                : zp;
            __builtin_amdgcn_global_load_lds(
                (const __attribute__((address_space(1))) uint32_t*)src,
                (__attribute__((address_space(3))) uint32_t*)
                    (xl + (slot * SLOT_B + (pass * 256 + (tid & ~63)) * 16) / 4),
                16, 0, 0);
        }
        // tail granules 512..527: lanes<16 of EVERY wave (uniform vmcnt,
        // idempotent duplicate writes of identical data)
        if (lane < 16) {
            const int jr = 512 + lane;
            const int px = jr >> 3;
            const int g  = jr & 7;
            const int ww = w0 - 1 + px;
            const bool v = ((unsigned)hh < 256u) & ((unsigned)ww < 256u);
            const uint32_t* src = v
                ? (const uint32_t*)(xbn + ((size_t)(hh * 256 + ww) << 7)
                                        + ((g ^ (px & 7)) << 4))
                : zp;
            __builtin_amdgcn_global_load_lds(
                (const __attribute__((address_space(1))) uint32_t*)src,
                (__attribute__((address_space(3))) uint32_t*)
                    (xl + (slot * SLOT_B + 512 * 16) / 4),
                16, 0, 0);
        }
    };

    // ---- prologue: rows L0..5 -> slots 0..5, one-time full drain ----
#pragma unroll
    for (int L = 0; L < 6; ++L) stage_row(L, h0 - 1 + L);
    __builtin_amdgcn_sched_barrier(0);
    asm volatile("s_waitcnt vmcnt(0)" ::: "memory");
    __builtin_amdgcn_s_barrier();
    __builtin_amdgcn_sched_barrier(0);

    // per-lane B byte offsets within a slot
    int boff[2][3];
#pragma unroll
    for (int s = 0; s < 2; ++s)
#pragma unroll
        for (int kw = 0; kw < 3; ++kw) {
            const int p = col + kw;
            boff[s][kw] = p * 128 + (((s * 4 + row4) ^ (p & 7)) << 4);
        }

    for (int c = 0; c < 8; ++c) {
        // ---- issue rows 2c+6, 2c+7 (consumed by chunk c+2) ----
        if (c < 6) {
            stage_row((2 * c + 6) & 7, h0 + 2 * c + 5);
            stage_row((2 * c + 7) & 7, h0 + 2 * c + 6);
        }

        // ---- compute output row h0 + 2c + wn (slots (2c..2c+3)&7) ----
        f32x4 acc[2][4];
#pragma unroll
        for (int mi = 0; mi < 2; ++mi)
#pragma unroll
            for (int ni = 0; ni < 4; ++ni) acc[mi][ni] = (f32x4){0.f, 0.f, 0.f, 0.f};

#pragma unroll
        for (int kh = 0; kh < 3; ++kh) {
            const int sl = (2 * c + wn + kh) & 7;
            const int mb = sl * SLOT_B;
#pragma unroll
            for (int kw = 0; kw < 3; ++kw) {
                const int t = kh * 3 + kw;
#pragma unroll
                for (int s = 0; s < 2; ++s) {
                    const short8 a0 = areg[t][0][s];
                    const short8 a1 = areg[t][1][s];
                    const char* bp = lb + mb + boff[s][kw];
                    short8 b0 = *reinterpret_cast<const short8*>(bp);
                    short8 b1 = *reinterpret_cast<const short8*>(bp + 2048);
                    short8 b2 = *reinterpret_cast<const short8*>(bp + 4096);
                    short8 b3 = *reinterpret_cast<const short8*>(bp + 6144);
                    acc[0][0] = __builtin_amdgcn_mfma_f32_16x16x32_bf16(a0, b0, acc[0][0], 0, 0, 0);
                    acc[1][0] = __builtin_amdgcn_mfma_f32_16x16x32_bf16(a1, b0, acc[1][0], 0, 0, 0);
                    acc[0][1] = __builtin_amdgcn_mfma_f32_16x16x32_bf16(a0, b1, acc[0][1], 0, 0, 0);
                    acc[1][1] = __builtin_amdgcn_mfma_f32_16x16x32_bf16(a1, b1, acc[1][1], 0, 0, 0);
                    acc[0][2] = __builtin_amdgcn_mfma_f32_16x16x32_bf16(a0, b2, acc[0][2], 0, 0, 0);
                    acc[1][2] = __builtin_amdgcn_mfma_f32_16x16x32_bf16(a1, b2, acc[1][2], 0, 0, 0);
                    acc[0][3] = __builtin_amdgcn_mfma_f32_16x16x32_bf16(a0, b3, acc[0][3], 0, 0, 0);
                    acc[1][3] = __builtin_amdgcn_mfma_f32_16x16x32_bf16(a1, b3, acc[1][3], 0, 0, 0);
                }
            }
        }

        // ---- counted barrier: keep this chunk's 6 DMA in flight; drain
        // everything older (prev DMA batch -> chunk c+1 rows ready; stores) ----
        __builtin_amdgcn_sched_barrier(0);
        asm volatile("s_waitcnt vmcnt(6)" ::: "memory");
        __builtin_amdgcn_s_barrier();
        __builtin_amdgcn_sched_barrier(0);

        // ---- store output row (fire-and-forget; drained at next barrier) ----
        const int rr = h0 + 2 * c + wn;
        const size_t ob = (size_t)n * CH_OUT * 65536 + (size_t)rr * 256 + w0;
#pragma unroll
        for (int mi = 0; mi < 2; ++mi)
#pragma unroll
            for (int reg = 0; reg < 4; ++reg) {
                const int co = cosplit * 64 + wq * 32 + mi * 16 + row4 * 4 + reg;
                float* op = out + ob + (size_t)co * 65536;
#pragma unroll
                for (int ni = 0; ni < 4; ++ni) op[ni * 16 + col] = acc[mi][ni][reg];
            }
    }
}

// ---------------------------------------------------------------------------
// Fallback (round-1 proven kernel) if ws too small.
// ---------------------------------------------------------------------------
__global__ void __launch_bounds__(256) nac_conv_fb(const float* __restrict__ x,
                                                   const uint32_t* __restrict__ Af,
                                                   float* __restrict__ out) {
    __shared__ uint32_t xl[8 * 272 * 4];
    unsigned bid = blockIdx.x;
    unsigned idx = (bid & 7u) * 1024u + (bid >> 3);
    int ht = idx & 127;
    int wt = (idx >> 7) & 3;
    int n  = idx >> 9;
    int h0 = ht * 2;
    int w0 = wt * 64;
    int tid = threadIdx.x;

    const float* xn = x + (size_t)n * CH_IN * HW * HW;
    for (int it = 0; it < 9; ++it) {
        int task = tid + it * 256;
        if (task < 2176) {
            int r   = task / 544;
            int rem = task - r * 544;
            int pg  = rem / 68;
            int c   = rem - pg * 68;
            int hrow = h0 - 1 + r;
            int w    = w0 - 1 + c;
            float v[8];
            if ((unsigned)hrow < 256u && (unsigned)w < 256u) {
                const float* p = xn + ((size_t)(pg * 8) * HW + hrow) * HW + w;
#pragma unroll
                for (int e = 0; e < 8; ++e) v[e] = p[(size_t)e * HW * HW];
            } else {
#pragma unroll
                for (int e = 0; e < 8; ++e) v[e] = 0.0f;
            }
            uint4 wd;
            wd.x = pack_bf16(v[0], v[1]);
            wd.y = pack_bf16(v[2], v[3]);
            wd.z = pack_bf16(v[4], v[5]);
            wd.w = pack_bf16(v[6], v[7]);
            *reinterpret_cast<uint4*>(&xl[(pg * 272 + r * 68 + c) * 4]) = wd;
        }
    }
    __syncthreads();

    int lane = tid & 63;
    int wv   = tid >> 6;
    int wm   = wv >> 1;
    int wn   = wv & 1;
    int row4 = lane >> 4;
    int col  = lane & 15;

    f32x4 acc[4][4];
#pragma unroll
    for (int mi = 0; mi < 4; ++mi)
#pragma unroll
        for (int ni = 0; ni < 4; ++ni) acc[mi][ni] = (f32x4){0.f, 0.f, 0.f, 0.f};

    const short8* Afr = reinterpret_cast<const short8*>(Af);
    for (int t = 0; t < 9; ++t) {
        int kh = t / 3, kw = t % 3;
        short8 a[2][4];
#pragma unroll
        for (int s = 0; s < 2; ++s)
#pragma unroll
            for (int mi = 0; mi < 4; ++mi)
                a[s][mi] = Afr[((t * 8 + (wm * 4 + mi)) * 2 + s) * 64 + lane];
#pragma unroll
        for (int s = 0; s < 2; ++s) {
            short8 b[4];
#pragma unroll
            for (int ni = 0; ni < 4; ++ni) {
                int pg = s * 4 + row4;
                int pp = (wn + kh) * 68 + ni * 16 + col + kw;
                b[ni] = *reinterpret_cast<const short8*>(&xl[(pg * 272 + pp) * 4]);
            }
#pragma unroll
            for (int mi = 0; mi < 4; ++mi)
#pragma unroll
                for (int ni = 0; ni < 4; ++ni)
                    acc[mi][ni] = __builtin_amdgcn_mfma_f32_16x16x32_bf16(
                        a[s][mi], b[ni], acc[mi][ni], 0, 0, 0);
        }
    }

#pragma unroll
    for (int mi = 0; mi < 4; ++mi) {
#pragma unroll
        for (int reg = 0; reg < 4; ++reg) {
            int co = wm * 64 + mi * 16 + row4 * 4 + reg;
            float* op = out + (((size_t)n * CH_OUT + co) * HW + (h0 + wn)) * HW + w0;
#pragma unroll
            for (int ni = 0; ni < 4; ++ni) op[ni * 16 + col] = acc[mi][ni][reg];
        }
    }
}

extern "C" void kernel_launch(void* const* d_in, const int* in_sizes, int n_in,
                              void* d_out, int out_size, void* d_ws, size_t ws_size,
                              hipStream_t stream) {
    const float* x  = (const float*)d_in[0];
    const float* Wh = (const float*)d_in[1];
    const float* Mh = (const float*)d_in[2];
    float* out = (float*)d_out;
    uint32_t* ws32 = (uint32_t*)d_ws;
    const uint32_t* Af = ws32;
    const uint32_t* zp = ws32 + ZP_BYTE / 4;
    uint32_t* xbuf = ws32 + XB_BYTE / 4;

    nac_prep16<<<36, 256, 0, stream>>>(Wh, Mh, ws32);
    if (ws_size >= WS_NEED) {
        nac_convert<<<4096, 256, 0, stream>>>(x, xbuf);
        nac_conv7<<<2048, 256, 0, stream>>>(xbuf, Af, out, zp);
    } else {
        nac_conv_fb<<<8192, 256, 0, stream>>>(x, Af, out);
    }
}

// Round 12
// 314.496 us; speedup vs baseline: 1.0024x; 1.0024x over previous
//
#include <hip/hip_runtime.h>
#include <hip/hip_bf16.h>
#include <stdint.h>

// ConvNACCell: out[n,co,h,w] = sum_{ci,kh,kw} x[n,ci,h+kh-1,w+kw-1] * W[co,ci,kh,kw]
// W = tanh(W_hat)*sigmoid(M_hat). Implicit GEMM, mfma_f32_16x16x32_bf16.
// Pass 1: x fp32 NCHW -> bf16 NHWC (ws). Pass 2: conv8 = conv7 skeleton with
//   * vmcnt(38) barriers: stores (32/wave/chunk) + DMA (6) stay in flight for
//     TWO chunk windows; only {stores_{c-2}, DMA_{c-1}} drained per barrier.
//     R11 post-mortem: vmcnt(6) drained prev stores every barrier -> measured
//     dur == exact zero-overlap pipe sum (179k MFMA + 147k LDS + 262k HBM cyc
//     per CU = 245us). This change buys stores a full extra chunk to drain.
//   * 64-row tiles (block = 64co x 64h x 64w, grid 512 = 2/CU, one round):
//     prologue once per CU, halo 66/64 = 1.03x.

#define CH_IN  64
#define CH_OUT 128
#define HW     256

typedef __attribute__((ext_vector_type(8))) short short8;   // 8 bf16
typedef __attribute__((ext_vector_type(4))) float f32x4;

// ws layout (bytes)
#define ZP_BYTE  147456u
#define XB_BYTE  147712u
#define WS_NEED  (147712ull + 134217728ull)

#define SLOT_B  8448          // one input row: 528 granules (66 px * 8 g) * 16 B
#define NSLOT   8             // ring slots (slot = L & 7)

static __device__ __forceinline__ uint32_t pack_bf16(float a, float b) {
    uint32_t ua = __builtin_bit_cast(uint32_t, a);
    uint32_t ub = __builtin_bit_cast(uint32_t, b);
    ua = (ua + 0x7FFFu + ((ua >> 16) & 1u)) >> 16;
    ub = (ub + 0x7FFFu + ((ub >> 16) & 1u));
    return (ua & 0xFFFFu) | (ub & 0xFFFF0000u);
}

// ---------------------------------------------------------------------------
// Prep: 16x16x32 A-fragment table + zero page.
//   frag[t][ms(8)][s(2)][lane]: elem j = A[co = ms*16 + (lane&15)]
//                                        [ci = s*32 + (lane>>4)*8 + j], tap t.
// ---------------------------------------------------------------------------
__global__ void __launch_bounds__(256) nac_prep16(const float* __restrict__ Wh,
                                                  const float* __restrict__ Mh,
                                                  uint32_t* __restrict__ ws32) {
    if (blockIdx.x == 0 && threadIdx.x < 64) ws32[ZP_BYTE / 4 + threadIdx.x] = 0;

    int f = blockIdx.x * 256 + threadIdx.x;   // 0..9215
    if (f >= 9 * 8 * 2 * 64) return;
    int lane = f & 63;
    int s    = (f >> 6) & 1;
    int ms   = (f >> 7) & 7;
    int t    = f >> 10;
    int co   = ms * 16 + (lane & 15);
    int ci0  = s * 32 + ((lane >> 4) << 3);

    uint32_t pk[4];
#pragma unroll
    for (int j2 = 0; j2 < 4; ++j2) {
        int ci = ci0 + 2 * j2;
        int k0 = ci * 9 + t;
        int k1 = k0 + 9;
        float w0 = tanhf(Wh[co * 576 + k0]);
        float m0 = Mh[co * 576 + k0];
        float w1 = tanhf(Wh[co * 576 + k1]);
        float m1 = Mh[co * 576 + k1];
        float v0 = w0 * (1.0f / (1.0f + expf(-m0)));
        float v1 = w1 * (1.0f / (1.0f + expf(-m1)));
        pk[j2] = pack_bf16(v0, v1);
    }
    int fragidx = ((t * 8 + ms) * 2 + s) * 64 + lane;
    reinterpret_cast<uint4*>(ws32)[fragidx] = make_uint4(pk[0], pk[1], pk[2], pk[3]);
}

// ---------------------------------------------------------------------------
// Convert: x [16,64,256,256] fp32 NCHW -> xb [16,256,256,64] bf16 NHWC.
// ---------------------------------------------------------------------------
__global__ void __launch_bounds__(256) nac_convert(const float* __restrict__ x,
                                                   uint32_t* __restrict__ xb) {
    int bid = blockIdx.x;            // 4096
    int h   = bid & 255;
    int n   = bid >> 8;
    int px  = threadIdx.x;
    const float* xr = x + ((size_t)n * CH_IN * HW + h) * HW + px;
    uint32_t* orow = xb + ((size_t)(n * HW + h) * HW + px) * 32;
#pragma unroll
    for (int g = 0; g < 8; ++g) {
        float v0 = xr[(size_t)(g * 8 + 0) * HW * HW];
        float v1 = xr[(size_t)(g * 8 + 1) * HW * HW];
        float v2 = xr[(size_t)(g * 8 + 2) * HW * HW];
        float v3 = xr[(size_t)(g * 8 + 3) * HW * HW];
        float v4 = xr[(size_t)(g * 8 + 4) * HW * HW];
        float v5 = xr[(size_t)(g * 8 + 5) * HW * HW];
        float v6 = xr[(size_t)(g * 8 + 6) * HW * HW];
        float v7 = xr[(size_t)(g * 8 + 7) * HW * HW];
        uint4 wd;
        wd.x = pack_bf16(v0, v1); wd.y = pack_bf16(v2, v3);
        wd.z = pack_bf16(v4, v5); wd.w = pack_bf16(v6, v7);
        *reinterpret_cast<uint4*>(orow + g * 4) = wd;
    }
}

// ---------------------------------------------------------------------------
// Conv8. Block = 64co x 64h x 64w, 256 threads, 4 waves = (wq co-quarter) x
// (wn row). A slice (36 frags) in 144 VGPR. LDS ring: 8 slots, slot L&7 =
// input row hh = h0+L-1. Chunk c (0..31): reads slots (2c..2c+3)&7, issues
// rows L=2c+6,2c+7 (lookahead-2; rows >65 go to the zero-page into dead
// slots, keeping per-wave VMEM counts uniform at 6 DMA + 32 stores/chunk).
// Barrier = s_waitcnt vmcnt(38) + s_barrier: drains {stores_{c-2}, DMA_{c-1}}
// only; stores ride across barriers with a 2-chunk drain window.
// ---------------------------------------------------------------------------
__global__ void __launch_bounds__(256, 2)
nac_conv8(const uint32_t* __restrict__ xb, const uint32_t* __restrict__ Af,
          float* __restrict__ out, const uint32_t* __restrict__ zp) {
    __shared__ __align__(1024) uint32_t xl[NSLOT * SLOT_B / 4];   // 67,584 B

    unsigned bid = blockIdx.x;
    unsigned idx = (bid & 7u) * 64u + (bid >> 3);   // bijective XCD swizzle (512)
    const int cosplit = idx & 1;                    // siblings adjacent -> same XCD
    const int ht = (idx >> 1) & 3;
    const int wt = (idx >> 3) & 3;
    const int n  = idx >> 5;
    const int h0 = ht * 64, w0 = wt * 64;

    const int tid  = threadIdx.x;
    const int lane = tid & 63;
    const int wv   = tid >> 6;      // 0..3
    const int wq   = wv >> 1;       // co quarter within the cosplit half
    const int wn   = wv & 1;        // row within chunk
    const int col  = lane & 15;
    const int row4 = lane >> 4;

    const char* xbn = reinterpret_cast<const char*>(xb) + ((size_t)n << 23);
    const char* lb  = reinterpret_cast<const char*>(xl);

    // ---- A slice into registers: 36 frags, coalesced 1KB loads, L2-hot ----
    const short8* Afr = reinterpret_cast<const short8*>(Af);
    short8 areg[9][2][2];
#pragma unroll
    for (int t = 0; t < 9; ++t)
#pragma unroll
        for (int mi = 0; mi < 2; ++mi)
#pragma unroll
            for (int s = 0; s < 2; ++s)
                areg[t][mi][s] =
                    Afr[((t * 8 + cosplit * 4 + wq * 2 + mi) * 2 + s) * 64 + lane];

    // ---- stage one input row into one ring slot: exactly 3 VMEM per wave ----
    auto stage_row = [&](int slot, int hh) {
#pragma unroll
        for (int pass = 0; pass < 2; ++pass) {
            const int jr = pass * 256 + tid;       // 0..511
            const int px = jr >> 3;
            const int g  = jr & 7;
            const int ww = w0 - 1 + px;
            const bool v = ((unsigned)hh < 256u) & ((unsigned)ww < 256u);
            const uint32_t* src = v
                ? (const uint32_t*)(xbn + ((size_t)(hh * 256 + ww) << 7)
                                        + ((g ^ (px & 7)) << 4))
                : zp;
            __builtin_amdgcn_global_load_lds(
                (const __attribute__((address_space(1))) uint32_t*)src,
                (__attribute__((address_space(3))) uint32_t*)
                    (xl + (slot * SLOT_B + (pass * 256 + (tid & ~63)) * 16) / 4),
                16, 0, 0);
        }
        // tail granules 512..527: lanes<16 of EVERY wave (uniform vmcnt,
        // idempotent duplicate writes of identical data)
        if (lane < 16) {
            const int jr = 512 + lane;
            const int px = jr >> 3;
            const int g  = jr & 7;
            const int ww = w0 - 1 + px;
            const bool v = ((unsigned)hh < 256u) & ((unsigned)ww < 256u);
            const uint32_t* src = v
                ? (const uint32_t*)(xbn + ((size_t)(hh * 256 + ww) << 7)
                                        + ((g ^ (px & 7)) << 4))
                : zp;
            __builtin_amdgcn_global_load_lds(
                (const __attribute__((address_space(1))) uint32_t*)src,
                (__attribute__((address_space(3))) uint32_t*)
                    (xl + (slot * SLOT_B + 512 * 16) / 4),
                16, 0, 0);
        }
    };

    // ---- prologue: rows L0..5 -> slots 0..5, one-time full drain ----
#pragma unroll
    for (int L = 0; L < 6; ++L) stage_row(L, h0 - 1 + L);
    __builtin_amdgcn_sched_barrier(0);
    asm volatile("s_waitcnt vmcnt(0)" ::: "memory");
    __builtin_amdgcn_s_barrier();
    __builtin_amdgcn_sched_barrier(0);

    // per-lane B byte offsets within a slot
    int boff[2][3];
#pragma unroll
    for (int s = 0; s < 2; ++s)
#pragma unroll
        for (int kw = 0; kw < 3; ++kw) {
            const int p = col + kw;
            boff[s][kw] = p * 128 + (((s * 4 + row4) ^ (p & 7)) << 4);
        }

    for (int c = 0; c < 32; ++c) {
        // ---- issue rows L=2c+6, 2c+7 (consumed by chunk c+2; L>65 -> zero
        // page into dead slots (2,3)/(4,5) at c=30/31, keeping counts uniform)
        {
            const int L0 = 2 * c + 6;
            const int L1 = 2 * c + 7;
            stage_row(L0 & 7, (L0 <= 65) ? (h0 + L0 - 1) : 300);
            stage_row(L1 & 7, (L1 <= 65) ? (h0 + L1 - 1) : 300);
        }

        // ---- compute output row h0 + 2c + wn (slots (2c..2c+3)&7) ----
        f32x4 acc[2][4];
#pragma unroll
        for (int mi = 0; mi < 2; ++mi)
#pragma unroll
            for (int ni = 0; ni < 4; ++ni) acc[mi][ni] = (f32x4){0.f, 0.f, 0.f, 0.f};

#pragma unroll
        for (int kh = 0; kh < 3; ++kh) {
            const int sl = (2 * c + wn + kh) & 7;
            const int mb = sl * SLOT_B;
#pragma unroll
            for (int kw = 0; kw < 3; ++kw) {
                const int t = kh * 3 + kw;
#pragma unroll
                for (int s = 0; s < 2; ++s) {
                    const short8 a0 = areg[t][0][s];
                    const short8 a1 = areg[t][1][s];
                    const char* bp = lb + mb + boff[s][kw];
                    short8 b0 = *reinterpret_cast<const short8*>(bp);
                    short8 b1 = *reinterpret_cast<const short8*>(bp + 2048);
                    short8 b2 = *reinterpret_cast<const short8*>(bp + 4096);
                    short8 b3 = *reinterpret_cast<const short8*>(bp + 6144);
                    acc[0][0] = __builtin_amdgcn_mfma_f32_16x16x32_bf16(a0, b0, acc[0][0], 0, 0, 0);
                    acc[1][0] = __builtin_amdgcn_mfma_f32_16x16x32_bf16(a1, b0, acc[1][0], 0, 0, 0);
                    acc[0][1] = __builtin_amdgcn_mfma_f32_16x16x32_bf16(a0, b1, acc[0][1], 0, 0, 0);
                    acc[1][1] = __builtin_amdgcn_mfma_f32_16x16x32_bf16(a1, b1, acc[1][1], 0, 0, 0);
                    acc[0][2] = __builtin_amdgcn_mfma_f32_16x16x32_bf16(a0, b2, acc[0][2], 0, 0, 0);
                    acc[1][2] = __builtin_amdgcn_mfma_f32_16x16x32_bf16(a1, b2, acc[1][2], 0, 0, 0);
                    acc[0][3] = __builtin_amdgcn_mfma_f32_16x16x32_bf16(a0, b3, acc[0][3], 0, 0, 0);
                    acc[1][3] = __builtin_amdgcn_mfma_f32_16x16x32_bf16(a1, b3, acc[1][3], 0, 0, 0);
                }
            }
        }

        // ---- barrier: vmcnt(38) = leave {stores_{c-1}(32) + DMA_c(6)} in
        // flight; drains stores_{c-2} and DMA_{c-1} (ready for chunk c+1) ----
        __builtin_amdgcn_sched_barrier(0);
        asm volatile("s_waitcnt vmcnt(38)" ::: "memory");
        __builtin_amdgcn_s_barrier();
        __builtin_amdgcn_sched_barrier(0);

        // ---- store output row (rides across the next barrier) ----
        const int rr = h0 + 2 * c + wn;
        const size_t ob = (size_t)n * CH_OUT * 65536 + (size_t)rr * 256 + w0;
#pragma unroll
        for (int mi = 0; mi < 2; ++mi)
#pragma unroll
            for (int reg = 0; reg < 4; ++reg) {
                const int co = cosplit * 64 + wq * 32 + mi * 16 + row4 * 4 + reg;
                float* op = out + ob + (size_t)co * 65536;
#pragma unroll
                for (int ni = 0; ni < 4; ++ni) op[ni * 16 + col] = acc[mi][ni][reg];
            }
    }
}

// ---------------------------------------------------------------------------
// Fallback (round-1 proven kernel) if ws too small.
// ---------------------------------------------------------------------------
__global__ void __launch_bounds__(256) nac_conv_fb(const float* __restrict__ x,
                                                   const uint32_t* __restrict__ Af,
                                                   float* __restrict__ out) {
    __shared__ uint32_t xl[8 * 272 * 4];
    unsigned bid = blockIdx.x;
    unsigned idx = (bid & 7u) * 1024u + (bid >> 3);
    int ht = idx & 127;
    int wt = (idx >> 7) & 3;
    int n  = idx >> 9;
    int h0 = ht * 2;
    int w0 = wt * 64;
    int tid = threadIdx.x;

    const float* xn = x + (size_t)n * CH_IN * HW * HW;
    for (int it = 0; it < 9; ++it) {
        int task = tid + it * 256;
        if (task < 2176) {
            int r   = task / 544;
            int rem = task - r * 544;
            int pg  = rem / 68;
            int c   = rem - pg * 68;
            int hrow = h0 - 1 + r;
            int w    = w0 - 1 + c;
            float v[8];
            if ((unsigned)hrow < 256u && (unsigned)w < 256u) {
                const float* p = xn + ((size_t)(pg * 8) * HW + hrow) * HW + w;
#pragma unroll
                for (int e = 0; e < 8; ++e) v[e] = p[(size_t)e * HW * HW];
            } else {
#pragma unroll
                for (int e = 0; e < 8; ++e) v[e] = 0.0f;
            }
            uint4 wd;
            wd.x = pack_bf16(v[0], v[1]);
            wd.y = pack_bf16(v[2], v[3]);
            wd.z = pack_bf16(v[4], v[5]);
            wd.w = pack_bf16(v[6], v[7]);
            *reinterpret_cast<uint4*>(&xl[(pg * 272 + r * 68 + c) * 4]) = wd;
        }
    }
    __syncthreads();

    int lane = tid & 63;
    int wv   = tid >> 6;
    int wm   = wv >> 1;
    int wn   = wv & 1;
    int row4 = lane >> 4;
    int col  = lane & 15;

    f32x4 acc[4][4];
#pragma unroll
    for (int mi = 0; mi < 4; ++mi)
#pragma unroll
        for (int ni = 0; ni < 4; ++ni) acc[mi][ni] = (f32x4){0.f, 0.f, 0.f, 0.f};

    const short8* Afr = reinterpret_cast<const short8*>(Af);
    for (int t = 0; t < 9; ++t) {
        int kh = t / 3, kw = t % 3;
        short8 a[2][4];
#pragma unroll
        for (int s = 0; s < 2; ++s)
#pragma unroll
            for (int mi = 0; mi < 4; ++mi)
                a[s][mi] = Afr[((t * 8 + (wm * 4 + mi)) * 2 + s) * 64 + lane];
#pragma unroll
        for (int s = 0; s < 2; ++s) {
            short8 b[4];
#pragma unroll
            for (int ni = 0; ni < 4; ++ni) {
                int pg = s * 4 + row4;
                int pp = (wn + kh) * 68 + ni * 16 + col + kw;
                b[ni] = *reinterpret_cast<const short8*>(&xl[(pg * 272 + pp) * 4]);
            }
#pragma unroll
            for (int mi = 0; mi < 4; ++mi)
#pragma unroll
                for (int ni = 0; ni < 4; ++ni)
                    acc[mi][ni] = __builtin_amdgcn_mfma_f32_16x16x32_bf16(
                        a[s][mi], b[ni], acc[mi][ni], 0, 0, 0);
        }
    }

#pragma unroll
    for (int mi = 0; mi < 4; ++mi) {
#pragma unroll
        for (int reg = 0; reg < 4; ++reg) {
            int co = wm * 64 + mi * 16 + row4 * 4 + reg;
            float* op = out + (((size_t)n * CH_OUT + co) * HW + (h0 + wn)) * HW + w0;
#pragma unroll
            for (int ni = 0; ni < 4; ++ni) op[ni * 16 + col] = acc[mi][ni][reg];
        }
    }
}

extern "C" void kernel_launch(void* const* d_in, const int* in_sizes, int n_in,
                              void* d_out, int out_size, void* d_ws, size_t ws_size,
                              hipStream_t stream) {
    const float* x  = (const float*)d_in[0];
    const float* Wh = (const float*)d_in[1];
    const float* Mh = (const float*)d_in[2];
    float* out = (float*)d_out;
    uint32_t* ws32 = (uint32_t*)d_ws;
    const uint32_t* Af = ws32;
    const uint32_t* zp = ws32 + ZP_BYTE / 4;
    uint32_t* xbuf = ws32 + XB_BYTE / 4;

    nac_prep16<<<36, 256, 0, stream>>>(Wh, Mh, ws32);
    if (ws_size >= WS_NEED) {
        nac_convert<<<4096, 256, 0, stream>>>(x, xbuf);
        nac_conv8<<<512, 256, 0, stream>>>(xbuf, Af, out, zp);
    } else {
        nac_conv_fb<<<8192, 256, 0, stream>>>(x, Af, out);
    }
}